// Round 2
// baseline (501.352 us; speedup 1.0000x reference)
//
#include <hip/hip_runtime.h>
#include <hip/hip_bf16.h>

// Problem constants
#define NA 8192      // oscillators in bank a (mask rows)
#define NB 8192      // oscillators in bank b (mask cols = GEMM K)
#define NBATCH 64
#define NC 128       // GEMM N: interleaved [cos_b, sin_b] columns, c=2b (cos), 2b+1 (sin)
#define BM 128       // output rows per block
#define WM 32        // output rows per wave (2 A-fragments of 16)
#define SPLITK 8
#define KCHUNK (NB / SPLITK)   // 1024
#define NBW (NB / 32)          // 256 u32 bit-words per mask row

// workspace layout
#define XT_BYTES   (NC * NB * 2)          // 2 MiB bf16 Xt (K-permuted)
#define BITS_OFF   XT_BYTES
#define BITS_BYTES (NA * (NB / 8))        // 8 MiB bitmask
#define CTR_OFF    (BITS_OFF + BITS_BYTES)
#define PPART_OFF  (CTR_OFF + 4096)       // SPLITK * NA * NC * 4 = 32 MiB

typedef __bf16 bf16x8 __attribute__((ext_vector_type(8)));
typedef float  f32x4  __attribute__((ext_vector_type(4)));

// K-permutation (per 256-column block, from int4+ballot compression):
//   column j  ->  k' = (j & ~255) | ((j & 3) << 6) | ((j & 255) >> 2)
//   inverse:  j = (k' & ~255) | ((k' & 63) << 2) | ((k' >> 6) & 3)

// ---------------- compress: int32 mask -> bitmask (k'-ordered) + popcount -----
__global__ __launch_bounds__(256) void compress_kernel(
    const int* __restrict__ mask, unsigned int* __restrict__ bits,
    int* __restrict__ count)
{
    const int lane   = threadIdx.x & 63;
    const int gwave  = (blockIdx.x * 256 + threadIdx.x) >> 6;
    const int nwaves = (gridDim.x * 256) >> 6;

    int cnt = 0;
    // each iter: 512 consecutive columns of one row (2 x int4 per lane)
    const int total_iters = NA * (NB / 512);
    for (int it = gwave; it < total_iters; it += nwaves) {
        const int r  = it >> 4;            // NB/512 = 16 iters per row
        const int j0 = (it & 15) << 9;
        const int4* p = reinterpret_cast<const int4*>(mask + (size_t)r * NB + j0);
        int4 v0 = p[lane];
        int4 v1 = p[lane + 64];

        unsigned long long b0 = __ballot(v0.x != 0);
        unsigned long long b1 = __ballot(v0.y != 0);
        unsigned long long b2 = __ballot(v0.z != 0);
        unsigned long long b3 = __ballot(v0.w != 0);
        unsigned long long b4 = __ballot(v1.x != 0);
        unsigned long long b5 = __ballot(v1.y != 0);
        unsigned long long b6 = __ballot(v1.z != 0);
        unsigned long long b7 = __ballot(v1.w != 0);

        cnt += __builtin_popcountll(b0) + __builtin_popcountll(b1)
             + __builtin_popcountll(b2) + __builtin_popcountll(b3)
             + __builtin_popcountll(b4) + __builtin_popcountll(b5)
             + __builtin_popcountll(b6) + __builtin_popcountll(b7);

        if (lane == 0) {
            uint4* o = reinterpret_cast<uint4*>(bits + (size_t)r * NBW + (j0 >> 5));
            o[0] = (uint4){(unsigned)b0, (unsigned)(b0 >> 32), (unsigned)b1, (unsigned)(b1 >> 32)};
            o[1] = (uint4){(unsigned)b2, (unsigned)(b2 >> 32), (unsigned)b3, (unsigned)(b3 >> 32)};
            o[2] = (uint4){(unsigned)b4, (unsigned)(b4 >> 32), (unsigned)b5, (unsigned)(b5 >> 32)};
            o[3] = (uint4){(unsigned)b6, (unsigned)(b6 >> 32), (unsigned)b7, (unsigned)(b7 >> 32)};
        }
    }
    if (lane == 0) atomicAdd(count, cnt);
}

// ---------------- prep: phases_b -> Xt[c][k'] (bf16, K-permuted) --------------
__global__ __launch_bounds__(256) void prep_b_kernel(
    const float* __restrict__ pb, __hip_bfloat16* __restrict__ Xt)
{
    int tid = blockIdx.x * 256 + threadIdx.x;   // 0 .. NBATCH*NB-1
    int b  = tid >> 13;
    int kp = tid & (NB - 1);                    // k' (output index, coalesced)
    int j  = (kp & ~255) | ((kp & 63) << 2) | ((kp >> 6) & 3);
    float ph = pb[(size_t)b * NB + j];
    float s, c;
    __sincosf(ph, &s, &c);
    Xt[(size_t)(2 * b) * NB + kp]     = __float2bfloat16(c);
    Xt[(size_t)(2 * b + 1) * NB + kp] = __float2bfloat16(s);
}

// ---------------- bit expansion: 8 bits -> 8 bf16 (0.0 / 1.0) ----------------
__device__ inline bf16x8 expand8(unsigned int byte) {
    uint4 u;
    u.x = ((((byte >> 1) & 1u) << 16) | (byte & 1u))          * 0x3F80u;
    u.y = ((((byte >> 3) & 1u) << 16) | ((byte >> 2) & 1u))   * 0x3F80u;
    u.z = ((((byte >> 5) & 1u) << 16) | ((byte >> 4) & 1u))   * 0x3F80u;
    u.w = ((((byte >> 7) & 1u) << 16) | ((byte >> 6) & 1u))   * 0x3F80u;
    return __builtin_bit_cast(bf16x8, u);
}

// ---------------- GEMM: P[i][c] = sum_k bits[i][k] * Xt[c][k] -----------------
// A-fragment (16x16x32 bf16): A[m=lane&15][k=quad*8+e]  <- one u32 bit-word/lane
// B-fragment:                 B[k=quad*8+e][n=lane&15]  <- contiguous 16B from Xt
// C/D:                        col=lane&15, row=quad*4+reg (measured m89/m91)
__global__ __launch_bounds__(256, 2) void gemm_kernel(
    const unsigned int* __restrict__ bits, const __hip_bfloat16* __restrict__ Xtg,
    float* __restrict__ Ppart)
{
    const int tid  = threadIdx.x;
    const int wave = tid >> 6;
    const int lane = tid & 63;
    const int quad = lane >> 4;
    const int m    = lane & 15;
    const int itile = blockIdx.x;       // 0..63
    const int kc    = blockIdx.y;       // 0..SPLITK-1
    const int k0    = kc * KCHUNK;

    const int rowbase = itile * BM + wave * WM;
    const ushort* xt = reinterpret_cast<const ushort*>(Xtg);
    const int qsh = quad * 8;

    f32x4 acc[2][8];
#pragma unroll
    for (int f = 0; f < 2; ++f)
#pragma unroll
        for (int t = 0; t < 8; ++t)
            acc[f][t] = (f32x4){0.f, 0.f, 0.f, 0.f};

    const unsigned int* w0p = bits + (size_t)(rowbase + m) * NBW;
    const unsigned int* w1p = bits + (size_t)(rowbase + 16 + m) * NBW;

    for (int kk = k0; kk < k0 + KCHUNK; kk += 32) {
        const int wi = kk >> 5;
        unsigned int w0 = w0p[wi];
        unsigned int w1 = w1p[wi];
        const int kq = kk + qsh;

        bf16x8 a0 = expand8((w0 >> qsh) & 0xFFu);
        bf16x8 a1 = expand8((w1 >> qsh) & 0xFFu);

#pragma unroll
        for (int t = 0; t < 8; ++t) {
            const bf16x8 bfrag = *reinterpret_cast<const bf16x8*>(
                xt + (size_t)(t * 16 + m) * NB + kq);
            acc[0][t] = __builtin_amdgcn_mfma_f32_16x16x32_bf16(a0, bfrag, acc[0][t], 0, 0, 0);
            acc[1][t] = __builtin_amdgcn_mfma_f32_16x16x32_bf16(a1, bfrag, acc[1][t], 0, 0, 0);
        }
    }

    float* pout = Ppart + (size_t)kc * NA * NC;
#pragma unroll
    for (int f = 0; f < 2; ++f)
#pragma unroll
        for (int t = 0; t < 8; ++t)
#pragma unroll
            for (int r = 0; r < 4; ++r) {
                int row = rowbase + f * 16 + quad * 4 + r;
                int col = t * 16 + m;
                pout[(size_t)row * NC + col] = acc[f][t][r];
            }
}

// ---------------- reduce: real/imag per batch ---------------------------------
__global__ __launch_bounds__(256) void reduce_kernel(
    const float* __restrict__ pa, const float* __restrict__ Ppart,
    float* __restrict__ realg, float* __restrict__ imagg)
{
    const int t = threadIdx.x;
    const int c = t & 127;
    const int half = t >> 7;
    const int b = c >> 1;
    const int odd = c & 1;
    const int i0 = blockIdx.x * 32;

    float pacc = 0.f, qacc = 0.f;
    for (int i = i0 + half; i < i0 + 32; i += 2) {
        float v = 0.f;
#pragma unroll
        for (int kc = 0; kc < SPLITK; ++kc)
            v += Ppart[(size_t)kc * NA * NC + (size_t)i * NC + c];
        float ph = pa[(size_t)b * NA + i];
        float sn, cs;
        __sincosf(ph, &sn, &cs);
        float yc = odd ? sn : cs;
        float yo = odd ? cs : sn;
        pacc += yc * v;
        qacc += odd ? -(yo * v) : (yo * v);
    }

    __shared__ float red[2][256];
    red[0][t] = pacc;
    red[1][t] = qacc;
    __syncthreads();
    if (t < 128) {
        red[0][t] = red[0][t] + red[0][t + 128];
        red[1][t] = red[1][t] + red[1][t + 128];
    }
    __syncthreads();
    if (t < 64) {
        float real = red[0][2 * t] + red[0][2 * t + 1];
        float imag = red[1][2 * t] + red[1][2 * t + 1];
        atomicAdd(&realg[t], real);
        atomicAdd(&imagg[t], imag);
    }
}

// ---------------- finalize ----------------------------------------------------
__global__ void finalize_kernel(const float* __restrict__ realg,
                                const float* __restrict__ imagg,
                                const int* __restrict__ count,
                                float* __restrict__ out)
{
    int t = threadIdx.x;
    if (t < NBATCH) {
        float r = realg[t], im = imagg[t];
        float n = fmaxf((float)(*count), 1.0f);
        out[t] = sqrtf(r * r + im * im) / n;
    }
}

extern "C" void kernel_launch(void* const* d_in, const int* in_sizes, int n_in,
                              void* d_out, int out_size, void* d_ws, size_t ws_size,
                              hipStream_t stream) {
    const float* pa   = (const float*)d_in[0];   // phases_a (64, 8192) f32
    const float* pb   = (const float*)d_in[1];   // phases_b (64, 8192) f32
    const int*   mask = (const int*)d_in[2];     // coupling_mask (8192, 8192) i32
    float* out = (float*)d_out;                  // (64,) f32

    char* ws = (char*)d_ws;
    __hip_bfloat16* Xt = (__hip_bfloat16*)ws;
    unsigned int* bitsw = (unsigned int*)(ws + BITS_OFF);
    float* realg = (float*)(ws + CTR_OFF);
    float* imagg = realg + 64;
    int*   count = (int*)(ws + CTR_OFF + 512);
    float* Ppart = (float*)(ws + PPART_OFF);

    // zero real/imag accumulators + count
    hipMemsetAsync(ws + CTR_OFF, 0, 4096, stream);

    compress_kernel<<<2048, 256, 0, stream>>>(mask, bitsw, count);

    prep_b_kernel<<<(NBATCH * NB) / 256, 256, 0, stream>>>(pb, Xt);

    dim3 g(NA / BM, SPLITK);
    gemm_kernel<<<g, 256, 0, stream>>>(bitsw, Xt, Ppart);

    reduce_kernel<<<NA / 32, 256, 0, stream>>>(pa, Ppart, realg, imagg);

    finalize_kernel<<<1, 64, 0, stream>>>(realg, imagg, count, out);
}

// Round 3
// 467.481 us; speedup vs baseline: 1.0725x; 1.0725x over previous
//
#include <hip/hip_runtime.h>
#include <hip/hip_bf16.h>

// Problem constants
#define NA 8192      // oscillators in bank a (mask rows)
#define NB 8192      // oscillators in bank b (mask cols = GEMM K)
#define NBATCH 64
#define NC 128       // GEMM N: interleaved [cos_b, sin_b] columns, c=2b (cos), 2b+1 (sin)
#define BM 128       // output rows per block
#define WM 32        // output rows per wave (2 A-fragments of 16)
#define SPLITK 8
#define KCHUNK (NB / SPLITK)   // 1024
#define NBW (NB / 32)          // 256 u32 bit-words per mask row

// workspace layout
#define XT_BYTES   (NC * NB * 2)          // 2 MiB bf16 XtF (fragment-ordered)
#define BITS_OFF   XT_BYTES
#define BITS_BYTES (NA * (NB / 8))        // 8 MiB bitmask
#define CTR_OFF    (BITS_OFF + BITS_BYTES)
#define PPART_OFF  (CTR_OFF + 4096)       // SPLITK * NA * NC * 4 = 32 MiB

typedef __bf16 bf16x8 __attribute__((ext_vector_type(8)));
typedef float  f32x4  __attribute__((ext_vector_type(4)));

// K-permutation induced by compress's int4+ballot bit order (512-col chunks):
//   k' -> j:  u=k'&511; widx=u>>5; bit=u&31;
//   j = (k'&~511) + ((widx>>3)<<8) + ((widx&1)<<7) + (bit<<2) + ((widx>>1)&3)
// A-bits and B (XtF) both use k' order, so the GEMM is oblivious to it.

// ---------------- compress: int32 mask -> bitmask (k'-ordered) + popcount -----
__global__ __launch_bounds__(256) void compress_kernel(
    const int* __restrict__ mask, unsigned int* __restrict__ bits,
    int* __restrict__ count)
{
    const int lane   = threadIdx.x & 63;
    const int gwave  = (blockIdx.x * 256 + threadIdx.x) >> 6;
    const int nwaves = (gridDim.x * 256) >> 6;

    int cnt = 0;
    const int total_iters = NA * (NB / 512);   // 512 cols of one row per iter
    for (int it = gwave; it < total_iters; it += nwaves) {
        const int r  = it >> 4;
        const int j0 = (it & 15) << 9;
        const int4* p = reinterpret_cast<const int4*>(mask + (size_t)r * NB + j0);
        int4 v0 = p[lane];
        int4 v1 = p[lane + 64];

        unsigned long long b0 = __ballot(v0.x != 0);
        unsigned long long b1 = __ballot(v0.y != 0);
        unsigned long long b2 = __ballot(v0.z != 0);
        unsigned long long b3 = __ballot(v0.w != 0);
        unsigned long long b4 = __ballot(v1.x != 0);
        unsigned long long b5 = __ballot(v1.y != 0);
        unsigned long long b6 = __ballot(v1.z != 0);
        unsigned long long b7 = __ballot(v1.w != 0);

        cnt += __builtin_popcountll(b0) + __builtin_popcountll(b1)
             + __builtin_popcountll(b2) + __builtin_popcountll(b3)
             + __builtin_popcountll(b4) + __builtin_popcountll(b5)
             + __builtin_popcountll(b6) + __builtin_popcountll(b7);

        if (lane == 0) {
            uint4* o = reinterpret_cast<uint4*>(bits + (size_t)r * NBW + (j0 >> 5));
            o[0] = (uint4){(unsigned)b0, (unsigned)(b0 >> 32), (unsigned)b1, (unsigned)(b1 >> 32)};
            o[1] = (uint4){(unsigned)b2, (unsigned)(b2 >> 32), (unsigned)b3, (unsigned)(b3 >> 32)};
            o[2] = (uint4){(unsigned)b4, (unsigned)(b4 >> 32), (unsigned)b5, (unsigned)(b5 >> 32)};
            o[3] = (uint4){(unsigned)b6, (unsigned)(b6 >> 32), (unsigned)b7, (unsigned)(b7 >> 32)};
        }
    }
    if (lane == 0) atomicAdd(count, cnt);
}

// ---------------- prep: phases_b -> XtF in MFMA B-fragment order --------------
// XtF element index: ((kstep*8 + t)*64 + quad*16 + m)*8 + e
//   where k' = kstep*32 + quad*8 + e, col c = t*16 + m (c=2b: cos, c=2b+1: sin)
__global__ __launch_bounds__(256) void prep_b_kernel(
    const float* __restrict__ pb, __hip_bfloat16* __restrict__ Xtf)
{
    int tid = blockIdx.x * 256 + threadIdx.x;   // 0 .. NBATCH*NB-1
    int b  = tid >> 13;
    int kp = tid & (NB - 1);                    // k'
    // invert the ballot permutation to find source column j
    int u = kp & 511;
    int widx = u >> 5;
    int bit = u & 31;
    int j = (kp & ~511) + ((widx >> 3) << 8) + ((widx & 1) << 7)
          + (bit << 2) + ((widx >> 1) & 3);

    float ph = pb[(size_t)b * NB + j];
    float s, c;
    __sincosf(ph, &s, &c);

    int kstep = kp >> 5;
    int quad  = (kp >> 3) & 3;
    int e     = kp & 7;
    int t     = b >> 3;            // (2b)>>4 == (2b+1)>>4
    int m0    = (2 * b) & 15;
    size_t base = ((size_t)(kstep * 8 + t) * 64 + quad * 16) * 8 + e;
    Xtf[base + (size_t)m0 * 8]       = __float2bfloat16(c);
    Xtf[base + (size_t)(m0 + 1) * 8] = __float2bfloat16(s);
}

// ---------------- bit expansion: 8 bits -> 8 bf16 (0.0 / 1.0) ----------------
__device__ inline bf16x8 expand8(unsigned int byte) {
    uint4 u;
    u.x = ((((byte >> 1) & 1u) << 16) | (byte & 1u))          * 0x3F80u;
    u.y = ((((byte >> 3) & 1u) << 16) | ((byte >> 2) & 1u))   * 0x3F80u;
    u.z = ((((byte >> 5) & 1u) << 16) | ((byte >> 4) & 1u))   * 0x3F80u;
    u.w = ((((byte >> 7) & 1u) << 16) | ((byte >> 6) & 1u))   * 0x3F80u;
    return __builtin_bit_cast(bf16x8, u);
}

// ---------------- GEMM: P[i][c] = sum_k bits[i][k'] * XtF ---------------------
// A-fragment: one u32 bit-word per lane-row (L1-resident, 8 KB/block)
// B-fragment: fully coalesced 1 KB/instruction from fragment-ordered XtF
__global__ __launch_bounds__(256, 2) void gemm_kernel(
    const unsigned int* __restrict__ bits, const __hip_bfloat16* __restrict__ Xtfg,
    float* __restrict__ Ppart)
{
    const int tid  = threadIdx.x;
    const int wave = tid >> 6;
    const int lane = tid & 63;
    const int quad = lane >> 4;
    const int m    = lane & 15;
    const int itile = blockIdx.x;       // 0..63
    const int kc    = blockIdx.y;       // 0..SPLITK-1
    const int k0    = kc * KCHUNK;

    const int rowbase = itile * BM + wave * WM;
    const bf16x8* __restrict__ xf = reinterpret_cast<const bf16x8*>(Xtfg);
    const int qsh = quad * 8;

    f32x4 acc[2][8];
#pragma unroll
    for (int f = 0; f < 2; ++f)
#pragma unroll
        for (int t = 0; t < 8; ++t)
            acc[f][t] = (f32x4){0.f, 0.f, 0.f, 0.f};

    const unsigned int* w0p = bits + (size_t)(rowbase + m) * NBW;
    const unsigned int* w1p = bits + (size_t)(rowbase + 16 + m) * NBW;

    for (int kk = k0; kk < k0 + KCHUNK; kk += 32) {
        const int wi = kk >> 5;
        unsigned int w0 = w0p[wi];
        unsigned int w1 = w1p[wi];

        bf16x8 a0 = expand8((w0 >> qsh) & 0xFFu);
        bf16x8 a1 = expand8((w1 >> qsh) & 0xFFu);

        const bf16x8* fx = xf + (size_t)wi * 8 * 64 + lane;
#pragma unroll
        for (int t = 0; t < 8; ++t) {
            const bf16x8 bfrag = fx[t * 64];
            acc[0][t] = __builtin_amdgcn_mfma_f32_16x16x32_bf16(a0, bfrag, acc[0][t], 0, 0, 0);
            acc[1][t] = __builtin_amdgcn_mfma_f32_16x16x32_bf16(a1, bfrag, acc[1][t], 0, 0, 0);
        }
    }

    float* pout = Ppart + (size_t)kc * NA * NC;
#pragma unroll
    for (int f = 0; f < 2; ++f)
#pragma unroll
        for (int t = 0; t < 8; ++t)
#pragma unroll
            for (int r = 0; r < 4; ++r) {
                int row = rowbase + f * 16 + quad * 4 + r;
                int col = t * 16 + m;
                pout[(size_t)row * NC + col] = acc[f][t][r];
            }
}

// ---------------- reduce: real/imag per batch ---------------------------------
__global__ __launch_bounds__(256) void reduce_kernel(
    const float* __restrict__ pa, const float* __restrict__ Ppart,
    float* __restrict__ realg, float* __restrict__ imagg)
{
    const int t = threadIdx.x;
    const int c = t & 127;
    const int half = t >> 7;
    const int b = c >> 1;
    const int odd = c & 1;
    const int i0 = blockIdx.x * 32;

    float pacc = 0.f, qacc = 0.f;
    for (int i = i0 + half; i < i0 + 32; i += 2) {
        float v = 0.f;
#pragma unroll
        for (int kc = 0; kc < SPLITK; ++kc)
            v += Ppart[(size_t)kc * NA * NC + (size_t)i * NC + c];
        float ph = pa[(size_t)b * NA + i];
        float sn, cs;
        __sincosf(ph, &sn, &cs);
        float yc = odd ? sn : cs;
        float yo = odd ? cs : sn;
        pacc += yc * v;
        qacc += odd ? -(yo * v) : (yo * v);
    }

    __shared__ float red[2][256];
    red[0][t] = pacc;
    red[1][t] = qacc;
    __syncthreads();
    if (t < 128) {
        red[0][t] = red[0][t] + red[0][t + 128];
        red[1][t] = red[1][t] + red[1][t + 128];
    }
    __syncthreads();
    if (t < 64) {
        float real = red[0][2 * t] + red[0][2 * t + 1];
        float imag = red[1][2 * t] + red[1][2 * t + 1];
        atomicAdd(&realg[t], real);
        atomicAdd(&imagg[t], imag);
    }
}

// ---------------- finalize ----------------------------------------------------
__global__ void finalize_kernel(const float* __restrict__ realg,
                                const float* __restrict__ imagg,
                                const int* __restrict__ count,
                                float* __restrict__ out)
{
    int t = threadIdx.x;
    if (t < NBATCH) {
        float r = realg[t], im = imagg[t];
        float n = fmaxf((float)(*count), 1.0f);
        out[t] = sqrtf(r * r + im * im) / n;
    }
}

extern "C" void kernel_launch(void* const* d_in, const int* in_sizes, int n_in,
                              void* d_out, int out_size, void* d_ws, size_t ws_size,
                              hipStream_t stream) {
    const float* pa   = (const float*)d_in[0];   // phases_a (64, 8192) f32
    const float* pb   = (const float*)d_in[1];   // phases_b (64, 8192) f32
    const int*   mask = (const int*)d_in[2];     // coupling_mask (8192, 8192) i32
    float* out = (float*)d_out;                  // (64,) f32

    char* ws = (char*)d_ws;
    __hip_bfloat16* Xtf = (__hip_bfloat16*)ws;
    unsigned int* bitsw = (unsigned int*)(ws + BITS_OFF);
    float* realg = (float*)(ws + CTR_OFF);
    float* imagg = realg + 64;
    int*   count = (int*)(ws + CTR_OFF + 512);
    float* Ppart = (float*)(ws + PPART_OFF);

    // zero real/imag accumulators + count
    hipMemsetAsync(ws + CTR_OFF, 0, 4096, stream);

    compress_kernel<<<2048, 256, 0, stream>>>(mask, bitsw, count);

    prep_b_kernel<<<(NBATCH * NB) / 256, 256, 0, stream>>>(pb, Xtf);

    dim3 g(NA / BM, SPLITK);
    gemm_kernel<<<g, 256, 0, stream>>>(bitsw, Xtf, Ppart);

    reduce_kernel<<<NA / 32, 256, 0, stream>>>(pa, Ppart, realg, imagg);

    finalize_kernel<<<1, 64, 0, stream>>>(realg, imagg, count, out);
}

// Round 4
// 433.385 us; speedup vs baseline: 1.1568x; 1.0787x over previous
//
#include <hip/hip_runtime.h>
#include <hip/hip_bf16.h>

// Problem constants
#define NA 8192      // oscillators in bank a (mask rows)
#define NB 8192      // oscillators in bank b (mask cols = GEMM K)
#define NBATCH 64
#define NC 128       // GEMM N: interleaved [cos_b, sin_b] cols, c=2b (cos), 2b+1 (sin)
#define BM 128       // output rows per block
#define WM 32        // output rows per wave (2 A-fragments of 16)
#define SPLITK 8
#define KCHUNK (NB / SPLITK)   // 1024

// workspace layout
#define XT_BYTES  (NC * NB * 2)           // 2 MiB bf16 XtF (fragment-ordered)
#define CTR_OFF   XT_BYTES
#define PPART_OFF (CTR_OFF + 4096)        // SPLITK * NA * NC * 4 = 32 MiB

typedef __bf16 bf16x8 __attribute__((ext_vector_type(8)));
typedef float  f32x4  __attribute__((ext_vector_type(4)));

// ---------------- prep: phases_b -> XtF in MFMA B-fragment order --------------
// Element (k, c) stored at ((kstep*8 + t)*64 + quad*16 + m)*8 + e
//   kstep=k>>5, quad=(k>>3)&3, e=k&7, t=c>>4, m=c&15  (natural k order)
__global__ __launch_bounds__(256) void prep_b_kernel(
    const float* __restrict__ pb, __hip_bfloat16* __restrict__ Xtf)
{
    int tid = blockIdx.x * 256 + threadIdx.x;   // 0 .. NBATCH*NB-1
    int b = tid >> 13;
    int k = tid & (NB - 1);

    float ph = pb[tid];
    float s, c;
    __sincosf(ph, &s, &c);

    int kstep = k >> 5;
    int quad  = (k >> 3) & 3;
    int e     = k & 7;
    int t     = b >> 3;            // (2b)>>4 == (2b+1)>>4
    int m0    = (2 * b) & 15;
    size_t base = ((size_t)(kstep * 8 + t) * 64 + quad * 16) * 8 + e;
    Xtf[base + (size_t)m0 * 8]       = __float2bfloat16(c);
    Xtf[base + (size_t)(m0 + 1) * 8] = __float2bfloat16(s);
}

// ---------------- fused GEMM: P[i][c] = sum_k mask[i][k] * X[k][c] ------------
// A-fragment (16x16x32 bf16): A[m=lane&15][k=quad*8+e] <- 2x int4 direct mask loads
// B-fragment: fully coalesced 1 KB/instruction from fragment-ordered XtF
// C/D: col=lane&15, row=quad*4+reg (measured m89/m91)
// Mask popcount folded in (wave-reduce + 1 atomic/wave).
__global__ __launch_bounds__(256, 2) void gemm_kernel(
    const int* __restrict__ mask, const __hip_bfloat16* __restrict__ Xtfg,
    float* __restrict__ Ppart, int* __restrict__ count)
{
    const int tid  = threadIdx.x;
    const int wave = tid >> 6;
    const int lane = tid & 63;
    const int quad = lane >> 4;
    const int m    = lane & 15;
    const int itile = blockIdx.x;       // 0..63
    const int kc    = blockIdx.y;       // 0..SPLITK-1
    const int k0    = kc * KCHUNK;

    const int rowbase = itile * BM + wave * WM;
    const bf16x8* __restrict__ xf = reinterpret_cast<const bf16x8*>(Xtfg);

    f32x4 acc[2][8];
#pragma unroll
    for (int f = 0; f < 2; ++f)
#pragma unroll
        for (int t = 0; t < 8; ++t)
            acc[f][t] = (f32x4){0.f, 0.f, 0.f, 0.f};

    int cnt = 0;

    for (int kk = k0; kk < k0 + KCHUNK; kk += 32) {
        const int kq = kk + quad * 8;

        bf16x8 a[2];
#pragma unroll
        for (int f = 0; f < 2; ++f) {
            const int4* p = reinterpret_cast<const int4*>(
                mask + (size_t)(rowbase + f * 16 + m) * NB + kq);
            int4 r0 = p[0];
            int4 r1 = p[1];
            cnt += r0.x + r0.y + r0.z + r0.w + r1.x + r1.y + r1.z + r1.w;
            uint4 u;
            u.x = (r0.x ? 0x3F80u : 0u) | (r0.y ? 0x3F800000u : 0u);
            u.y = (r0.z ? 0x3F80u : 0u) | (r0.w ? 0x3F800000u : 0u);
            u.z = (r1.x ? 0x3F80u : 0u) | (r1.y ? 0x3F800000u : 0u);
            u.w = (r1.z ? 0x3F80u : 0u) | (r1.w ? 0x3F800000u : 0u);
            a[f] = __builtin_bit_cast(bf16x8, u);
        }

        const bf16x8* fx = xf + (size_t)(kk >> 5) * 8 * 64 + lane;
#pragma unroll
        for (int t = 0; t < 8; ++t) {
            const bf16x8 bfrag = fx[t * 64];
            acc[0][t] = __builtin_amdgcn_mfma_f32_16x16x32_bf16(a[0], bfrag, acc[0][t], 0, 0, 0);
            acc[1][t] = __builtin_amdgcn_mfma_f32_16x16x32_bf16(a[1], bfrag, acc[1][t], 0, 0, 0);
        }
    }

    // epilogue: write split-K partial tile
    float* pout = Ppart + (size_t)kc * NA * NC;
#pragma unroll
    for (int f = 0; f < 2; ++f)
#pragma unroll
        for (int t = 0; t < 8; ++t)
#pragma unroll
            for (int r = 0; r < 4; ++r) {
                int row = rowbase + f * 16 + quad * 4 + r;
                int col = t * 16 + m;
                pout[(size_t)row * NC + col] = acc[f][t][r];
            }

    // mask popcount: wave reduce then one atomic per wave
#pragma unroll
    for (int off = 32; off > 0; off >>= 1) cnt += __shfl_down(cnt, off);
    if (lane == 0) atomicAdd(count, cnt);
}

// ---------------- reduce: real/imag per batch ---------------------------------
__global__ __launch_bounds__(256) void reduce_kernel(
    const float* __restrict__ pa, const float* __restrict__ Ppart,
    float* __restrict__ realg, float* __restrict__ imagg)
{
    const int t = threadIdx.x;
    const int c = t & 127;
    const int half = t >> 7;
    const int b = c >> 1;
    const int odd = c & 1;
    const int i0 = blockIdx.x * 32;

    float pacc = 0.f, qacc = 0.f;
    for (int i = i0 + half; i < i0 + 32; i += 2) {
        float v = 0.f;
#pragma unroll
        for (int kc = 0; kc < SPLITK; ++kc)
            v += Ppart[(size_t)kc * NA * NC + (size_t)i * NC + c];
        float ph = pa[(size_t)b * NA + i];
        float sn, cs;
        __sincosf(ph, &sn, &cs);
        float yc = odd ? sn : cs;
        float yo = odd ? cs : sn;
        pacc += yc * v;
        qacc += odd ? -(yo * v) : (yo * v);
    }

    __shared__ float red[2][256];
    red[0][t] = pacc;
    red[1][t] = qacc;
    __syncthreads();
    if (t < 128) {
        red[0][t] = red[0][t] + red[0][t + 128];
        red[1][t] = red[1][t] + red[1][t + 128];
    }
    __syncthreads();
    if (t < 64) {
        float real = red[0][2 * t] + red[0][2 * t + 1];
        float imag = red[1][2 * t] + red[1][2 * t + 1];
        atomicAdd(&realg[t], real);
        atomicAdd(&imagg[t], imag);
    }
}

// ---------------- finalize ----------------------------------------------------
__global__ void finalize_kernel(const float* __restrict__ realg,
                                const float* __restrict__ imagg,
                                const int* __restrict__ count,
                                float* __restrict__ out)
{
    int t = threadIdx.x;
    if (t < NBATCH) {
        float r = realg[t], im = imagg[t];
        float n = fmaxf((float)(*count), 1.0f);
        out[t] = sqrtf(r * r + im * im) / n;
    }
}

extern "C" void kernel_launch(void* const* d_in, const int* in_sizes, int n_in,
                              void* d_out, int out_size, void* d_ws, size_t ws_size,
                              hipStream_t stream) {
    const float* pa   = (const float*)d_in[0];   // phases_a (64, 8192) f32
    const float* pb   = (const float*)d_in[1];   // phases_b (64, 8192) f32
    const int*   mask = (const int*)d_in[2];     // coupling_mask (8192, 8192) i32
    float* out = (float*)d_out;                  // (64,) f32

    char* ws = (char*)d_ws;
    __hip_bfloat16* Xtf = (__hip_bfloat16*)ws;
    float* realg = (float*)(ws + CTR_OFF);
    float* imagg = realg + 64;
    int*   count = (int*)(ws + CTR_OFF + 512);
    float* Ppart = (float*)(ws + PPART_OFF);

    // zero real/imag accumulators + count
    hipMemsetAsync(ws + CTR_OFF, 0, 4096, stream);

    prep_b_kernel<<<(NBATCH * NB) / 256, 256, 0, stream>>>(pb, Xtf);

    dim3 g(NA / BM, SPLITK);
    gemm_kernel<<<g, 256, 0, stream>>>(mask, Xtf, Ppart, count);

    reduce_kernel<<<NA / 32, 256, 0, stream>>>(pa, Ppart, realg, imagg);

    finalize_kernel<<<1, 64, 0, stream>>>(realg, imagg, count, out);
}

// Round 5
// 419.661 us; speedup vs baseline: 1.1947x; 1.0327x over previous
//
#include <hip/hip_runtime.h>
#include <hip/hip_bf16.h>

// Problem constants
#define NA 8192      // oscillators in bank a (mask rows)
#define NB 8192      // oscillators in bank b (mask cols = GEMM K)
#define NBATCH 64
#define NC 128       // GEMM N: interleaved [cos_b, sin_b] cols, c=2b (cos), 2b+1 (sin)
#define BM 128       // output rows per block
#define WM 32        // output rows per wave (2 A-fragments of 16)
#define SPLITK 8
#define KCHUNK (NB / SPLITK)   // 1024
#define NBLK (SPLITK * NA / BM)  // 512 gemm blocks

// workspace layout
#define XT_BYTES (NC * NB * 2)            // 2 MiB bf16 XtF (fragment-ordered)
#define CTR_OFF  XT_BYTES                 // count (int)
#define PBLK_OFF (CTR_OFF + 512)          // NBLK * 128 f32 block partials (256 KiB)

typedef __bf16 bf16x8 __attribute__((ext_vector_type(8)));
typedef float  f32x4  __attribute__((ext_vector_type(4)));
typedef int    ivec4  __attribute__((ext_vector_type(4)));

// ---------------- prep: phases_b -> XtF in MFMA B-fragment order --------------
// Element (k, c) stored at ((kstep*8 + t)*64 + quad*16 + m)*8 + e
//   kstep=k>>5, quad=(k>>3)&3, e=k&7, t=c>>4, m=c&15  (natural k order)
__global__ __launch_bounds__(256) void prep_b_kernel(
    const float* __restrict__ pb, __hip_bfloat16* __restrict__ Xtf)
{
    int tid = blockIdx.x * 256 + threadIdx.x;   // 0 .. NBATCH*NB-1
    int b = tid >> 13;
    int k = tid & (NB - 1);

    float ph = pb[tid];
    float s, c;
    __sincosf(ph, &s, &c);

    int kstep = k >> 5;
    int quad  = (k >> 3) & 3;
    int e     = k & 7;
    int t     = b >> 3;            // (2b)>>4 == (2b+1)>>4
    int m0    = (2 * b) & 15;
    size_t base = ((size_t)(kstep * 8 + t) * 64 + quad * 16) * 8 + e;
    Xtf[base + (size_t)m0 * 8]       = __float2bfloat16(c);
    Xtf[base + (size_t)(m0 + 1) * 8] = __float2bfloat16(s);
}

// ---------------- fused GEMM + batch-reduce epilogue --------------------------
// P[i][c] = sum_k mask[i][k] * X[k][c]  (never materialized)
// A-frag: 2x nontemporal int4 mask loads/lane; B-frag: coalesced 1 KB from XtF
// C/D: col=lane&15, row=quad*4+reg (measured m89/m91)
// Epilogue: real_b += ca[b,i]*P[i,2b] + sa[b,i]*P[i,2b+1]
//           imag_b += sa[b,i]*P[i,2b] - ca[b,i]*P[i,2b+1]
// reduced per-block into Pblk[bid][2b+comp]; popcount via wave atomic.
__global__ __launch_bounds__(256, 2) void gemm_kernel(
    const int* __restrict__ mask, const __hip_bfloat16* __restrict__ Xtfg,
    const float* __restrict__ pa,
    float* __restrict__ Pblk, int* __restrict__ count)
{
    const int tid  = threadIdx.x;
    const int wave = tid >> 6;
    const int lane = tid & 63;
    const int quad = lane >> 4;
    const int m    = lane & 15;
    const int itile = blockIdx.x;       // 0..63
    const int kc    = blockIdx.y;       // 0..SPLITK-1
    const int k0    = kc * KCHUNK;

    const int rowbase = itile * BM + wave * WM;
    const bf16x8* __restrict__ xf = reinterpret_cast<const bf16x8*>(Xtfg);

    f32x4 acc[2][8];
#pragma unroll
    for (int f = 0; f < 2; ++f)
#pragma unroll
        for (int t = 0; t < 8; ++t)
            acc[f][t] = (f32x4){0.f, 0.f, 0.f, 0.f};

    int cnt = 0;

    for (int kk = k0; kk < k0 + KCHUNK; kk += 32) {
        const int kq = kk + quad * 8;

        bf16x8 a[2];
#pragma unroll
        for (int f = 0; f < 2; ++f) {
            const ivec4* p = reinterpret_cast<const ivec4*>(
                mask + (size_t)(rowbase + f * 16 + m) * NB + kq);
            ivec4 r0 = __builtin_nontemporal_load(p);
            ivec4 r1 = __builtin_nontemporal_load(p + 1);
            cnt += r0.x + r0.y + r0.z + r0.w + r1.x + r1.y + r1.z + r1.w;
            uint4 u;
            u.x = (r0.x ? 0x3F80u : 0u) | (r0.y ? 0x3F800000u : 0u);
            u.y = (r0.z ? 0x3F80u : 0u) | (r0.w ? 0x3F800000u : 0u);
            u.z = (r1.x ? 0x3F80u : 0u) | (r1.y ? 0x3F800000u : 0u);
            u.w = (r1.z ? 0x3F80u : 0u) | (r1.w ? 0x3F800000u : 0u);
            a[f] = __builtin_bit_cast(bf16x8, u);
        }

        const bf16x8* fx = xf + (size_t)(kk >> 5) * 8 * 64 + lane;
#pragma unroll
        for (int t = 0; t < 8; ++t) {
            const bf16x8 bfrag = fx[t * 64];
            acc[0][t] = __builtin_amdgcn_mfma_f32_16x16x32_bf16(a[0], bfrag, acc[0][t], 0, 0, 0);
            acc[1][t] = __builtin_amdgcn_mfma_f32_16x16x32_bf16(a[1], bfrag, acc[1][t], 0, 0, 0);
        }
    }

    // ---- fused epilogue: project partial P onto (ca,sa) and reduce ----
    __shared__ float lred[4][64][2];
    const int odd = m & 1;

#pragma unroll
    for (int t = 0; t < 8; ++t) {
        const int b = t * 8 + (m >> 1);           // batch index for this column
        float rc = 0.f, ic = 0.f;
#pragma unroll
        for (int f = 0; f < 2; ++f)
#pragma unroll
            for (int r = 0; r < 4; ++r) {
                int row = rowbase + f * 16 + quad * 4 + r;
                float ph = pa[(size_t)b * NA + row];
                float sn, cs;
                __sincosf(ph, &sn, &cs);
                float Ax = odd ? sn : cs;          // real-part weight
                float Bx = odd ? -cs : sn;         // imag-part weight
                rc = fmaf(Ax, acc[f][t][r], rc);
                ic = fmaf(Bx, acc[f][t][r], ic);
            }
        // combine col pair (even+odd), then the 4 quads
        rc += __shfl_xor(rc, 1);  ic += __shfl_xor(ic, 1);
        rc += __shfl_xor(rc, 16); ic += __shfl_xor(ic, 16);
        rc += __shfl_xor(rc, 32); ic += __shfl_xor(ic, 32);
        if (quad == 0 && !odd) {
            lred[wave][b][0] = rc;
            lred[wave][b][1] = ic;
        }
    }
    __syncthreads();

    if (tid < 128) {
        float s = lred[0][tid >> 1][tid & 1] + lred[1][tid >> 1][tid & 1]
                + lred[2][tid >> 1][tid & 1] + lred[3][tid >> 1][tid & 1];
        int bid = blockIdx.y * 64 + blockIdx.x;
        Pblk[(size_t)bid * 128 + tid] = s;
    }

    // mask popcount: wave reduce then one atomic per wave
#pragma unroll
    for (int off = 32; off > 0; off >>= 1) cnt += __shfl_down(cnt, off);
    if (lane == 0) atomicAdd(count, cnt);
}

// ---------------- final: sum block partials, magnitude, normalize -------------
__global__ __launch_bounds__(512) void final_kernel(
    const float* __restrict__ Pblk, const int* __restrict__ count,
    float* __restrict__ out)
{
    const int t = threadIdx.x;          // 0..511
    const int grp = t & 3;              // 4 threads per value
    const int idx = t >> 2;             // 0..127 = 2b+comp

    float s = 0.f;
#pragma unroll 8
    for (int blk = grp * (NBLK / 4); blk < (grp + 1) * (NBLK / 4); ++blk)
        s += Pblk[(size_t)blk * 128 + idx];
    s += __shfl_xor(s, 1);
    s += __shfl_xor(s, 2);

    __shared__ float red[128];
    if (grp == 0) red[idx] = s;
    __syncthreads();

    if (t < NBATCH) {
        float r = red[2 * t], im = red[2 * t + 1];
        float n = fmaxf((float)(*count), 1.0f);
        out[t] = sqrtf(r * r + im * im) / n;
    }
}

extern "C" void kernel_launch(void* const* d_in, const int* in_sizes, int n_in,
                              void* d_out, int out_size, void* d_ws, size_t ws_size,
                              hipStream_t stream) {
    const float* pa   = (const float*)d_in[0];   // phases_a (64, 8192) f32
    const float* pb   = (const float*)d_in[1];   // phases_b (64, 8192) f32
    const int*   mask = (const int*)d_in[2];     // coupling_mask (8192, 8192) i32
    float* out = (float*)d_out;                  // (64,) f32

    char* ws = (char*)d_ws;
    __hip_bfloat16* Xtf = (__hip_bfloat16*)ws;
    int*   count = (int*)(ws + CTR_OFF);
    float* Pblk  = (float*)(ws + PBLK_OFF);

    // zero the popcount accumulator (ws is poisoned 0xAA before each call)
    hipMemsetAsync(ws + CTR_OFF, 0, 512, stream);

    prep_b_kernel<<<(NBATCH * NB) / 256, 256, 0, stream>>>(pb, Xtf);

    dim3 g(NA / BM, SPLITK);
    gemm_kernel<<<g, 256, 0, stream>>>(mask, Xtf, pa, Pblk, count);

    final_kernel<<<1, 512, 0, stream>>>(Pblk, count, out);
}